// Round 2
// 1343.169 us; speedup vs baseline: 1.0170x; 1.0170x over previous
//
#include <hip/hip_runtime.h>

// Turkish-aware cross-entropy: mean over rows of
//   (logsumexp(pred[i]) - pred[i][target[i]]) * scale(argmax(pred[i]), target[i])
// scale = 0.8 if argmax-char and target-char fall in the same Turkish
// similar-chars group {i/ı, o/ö, u/ü, g/ğ}, else 1.0.
//
// N=524288, V=512. HBM-bound ideal: 1.07 GB single pass ≈ 170 µs @ 6.3 TB/s.
//
// R2 = R1 resubmitted verbatim (R1 bench was an infra failure, no signal).
// R1 change vs baseline: 16-lane-group softmax (4 rows/wave) instead of
// one row per wave. DS shuffle ops drop 24/row -> 3/row, butterfly depth
// 6 -> 4 levels, 4x memory in flight per wave-iteration. Target logit is
// loaded directly (L1-resident, same lines as the row stream) instead of
// being reduced through the butterfly.

#define V 512

// group id per codepoint (0 = none). All group chars < 512.
__device__ __forceinline__ int grp(int c) {
    if (c == 105 || c == 305) return 1;  // i, ı
    if (c == 111 || c == 246) return 2;  // o, ö
    if (c == 117 || c == 252) return 3;  // u, ü
    if (c == 103 || c == 287) return 4;  // g, ğ
    return 0;
}

__global__ __launch_bounds__(256) void turkish_loss_kernel(
    const float* __restrict__ pred, const int* __restrict__ target,
    float* __restrict__ ws_sum, int N)
{
    __shared__ float wave_part[4];
    const int lane = threadIdx.x & 63;
    const int wid  = threadIdx.x >> 6;          // wave id in block (0..3)
    const int sub  = lane >> 4;                 // which of the wave's 4 rows
    const int gl   = lane & 15;                 // lane within the 16-lane row group
    const int gquad = blockIdx.x * 4 + wid;     // global wave (= row-quad) id
    const int nquad = gridDim.x * 4;

    float acc = 0.0f;

    for (int q = gquad; (q << 2) < N; q += nquad) {
        int row = (q << 2) + sub;
        const bool valid = row < N;
        if (!valid) row = 0;                    // clamped dummy; leader skips acc
        const float* rp = pred + (size_t)row * V;
        const int t = target[row];
        const float tv = rp[t];                 // same cache lines as the stream
        float4 d[8];
        const float4* p4 = (const float4*)rp;
        // per k: 16 lanes read a contiguous 256 B slice of the row
        #pragma unroll
        for (int k = 0; k < 8; ++k) d[k] = p4[gl + 16 * k];

        // ---- local max + argmax (first occurrence) over this lane's 32 elems
        // lane's element (k,j) is column 64k + 4*gl + j: ascending scan order,
        // so strict > keeps the earliest column.
        float m = d[0].x; int mi = 4 * gl;
        #pragma unroll
        for (int k = 0; k < 8; ++k) {
            const float vv[4] = {d[k].x, d[k].y, d[k].z, d[k].w};
            #pragma unroll
            for (int j = 0; j < 4; ++j) {
                const int col = 64 * k + 4 * gl + j;
                if (vv[j] > m) { m = vv[j]; mi = col; }
            }
        }

        // ---- 16-lane butterfly argmax (first occurrence on ties) ----
        #pragma unroll
        for (int off = 1; off < 16; off <<= 1) {
            const float m2 = __shfl_xor(m, off);
            const int   i2 = __shfl_xor(mi, off);
            if (m2 > m || (m2 == m && i2 < mi)) { m = m2; mi = i2; }
        }

        // ---- sumexp ----
        float s = 0.0f;
        #pragma unroll
        for (int k = 0; k < 8; ++k)
            s += __expf(d[k].x - m) + __expf(d[k].y - m)
               + __expf(d[k].z - m) + __expf(d[k].w - m);
        #pragma unroll
        for (int off = 1; off < 16; off <<= 1) s += __shfl_xor(s, off);

        // group leader accumulates this row's scaled loss
        if (gl == 0 && valid) {
            const float loss = m + __logf(s) - tv;
            const int gp = grp(mi), gt = grp(t);
            acc += loss * ((gp > 0 && gp == gt) ? 0.8f : 1.0f);
        }
    }

    // fold the 4 group leaders (lanes 0,16,32,48) into lane 0
    acc += __shfl_xor(acc, 16);
    acc += __shfl_xor(acc, 32);
    if (lane == 0) wave_part[wid] = acc;
    __syncthreads();
    if (threadIdx.x == 0) {
        float bsum = wave_part[0] + wave_part[1] + wave_part[2] + wave_part[3];
        atomicAdd(ws_sum, bsum);
    }
}

__global__ void turkish_loss_finalize(const float* __restrict__ ws_sum,
                                      float* __restrict__ out, float invN)
{
    out[0] = ws_sum[0] * invN;
}

extern "C" void kernel_launch(void* const* d_in, const int* in_sizes, int n_in,
                              void* d_out, int out_size, void* d_ws, size_t ws_size,
                              hipStream_t stream) {
    const float* pred   = (const float*)d_in[0];
    const int*   target = (const int*)d_in[1];
    const int N = in_sizes[1];          // 524288 rows
    float* ws_sum = (float*)d_ws;

    // harness re-poisons d_ws to 0xAA before every timed launch
    hipMemsetAsync(d_ws, 0, sizeof(float), stream);

    // 2048 blocks x 256 thr = 8192 waves; 4 rows/wave-iter, 16 iterations
    turkish_loss_kernel<<<dim3(2048), dim3(256), 0, stream>>>(pred, target, ws_sum, N);
    turkish_loss_finalize<<<1, 1, 0, stream>>>(ws_sum, (float*)d_out, 1.0f / (float)N);
}